// Round 4
// baseline (405.911 us; speedup 1.0000x reference)
//
#include <hip/hip_runtime.h>
#include <hip/hip_cooperative_groups.h>
#include <math.h>

namespace cg = cooperative_groups;

#define B 8
#define C 64
#define HIN 224
#define WIN 224
#define PLANE (HIN*WIN)        // 50176
#define PLANE4 (PLANE/4)       // 12544
#define HALF4 (PLANE4/2)       // 6272
#define OH 64
#define OW 128
#define OUT_PER_BC (OH*OW)     // 8192
#define POOLED_SIZE (B*C*OH*OW) // 4194304
#define NGRID (OH*OW)          // 8192 coords per batch

// ws layout (floats):
// [0, 1024)            : partial sums [bc][half]
// [4096, 4096+131072)  : coords [b][8192] float2 (ix, iy)
#define WS_PARTIAL 0
#define WS_COORDS 4096

#define PI_F 3.14159265358979323846f

__device__ __forceinline__ float bilinear(const float* __restrict__ p,
                                          float ix, float iy) {
    float x0f = floorf(ix), y0f = floorf(iy);
    int x0 = (int)x0f, y0 = (int)y0f;
    float wx = ix - x0f, wy = iy - y0f;
    int x1 = min(x0 + 1, WIN - 1);
    int y1 = min(y0 + 1, HIN - 1);
    const float* r0 = p + y0 * WIN;
    const float* r1 = p + y1 * WIN;
    float v00 = r0[x0], v01 = r0[x1], v10 = r1[x0], v11 = r1[x1];
    float v0 = v00 + (v01 - v00) * wx;
    float v1 = v10 + (v11 - v10) * wx;
    return v0 + (v1 - v0) * wy;
}

// ---------- phase A body: GAP partial (half plane) + const-region fill ------
__device__ __forceinline__ void phaseA(int blk, int tid,
                                       const float* __restrict__ x,
                                       const float* __restrict__ l_t,
                                       float* __restrict__ ws,
                                       float* __restrict__ out,
                                       float* lds4) {
    int bc = blk >> 1, half = blk & 1;
    int b  = bc >> 6;

    const float4* p = (const float4*)x + (size_t)bc * PLANE4 + half * HALF4;
    float s = 0.f;
#pragma unroll
    for (int k = 0; k < 24; ++k) {
        float4 v = p[tid + k * 256];
        s += (v.x + v.y) + (v.z + v.w);
    }
    if (tid < HALF4 - 24 * 256) {   // remainder: 128 float4s
        float4 v = p[tid + 24 * 256];
        s += (v.x + v.y) + (v.z + v.w);
    }

    // Constant region: grid == (0,0)+l_t outside the 64x128 fine corner ->
    // all pooled outputs with h>=16 or w>=32 equal ONE bilinear sample.
    const float* plane = x + (size_t)bc * PLANE;
    float gx = l_t[b * 2 + 0], gy = l_t[b * 2 + 1];
    float ixc = fminf(fmaxf(((gx + 1.f) * (float)WIN - 1.f) * 0.5f, 0.f), (float)(WIN - 1));
    float iyc = fminf(fmaxf(((gy + 1.f) * (float)HIN - 1.f) * 0.5f, 0.f), (float)(HIN - 1));
    float vc = bilinear(plane, ixc, iyc);   // wave-uniform address: 1 txn
    float4 vc4 = make_float4(vc, vc, vc, vc);

    // const-region f4 enumeration: idx<384 -> rows 0..15 cols 8..31;
    // else rows 16..63 all 32 cols. 1920 total, 960 per half.
    float4* o4 = (float4*)(out + (size_t)bc * OUT_PER_BC);
#pragma unroll
    for (int k = 0; k < 4; ++k) {
        int local = tid + k * 256;
        if (local < 960) {
            int idx = half * 960 + local;
            int row, col;
            if (idx < 384) { row = idx / 24; col = 8 + (idx - row * 24); }
            else { int t2 = idx - 384; row = 16 + (t2 >> 5); col = t2 & 31; }
            o4[row * 32 + col] = vc4;
        }
    }

    // wave reduce + cross-wave via LDS
    for (int off = 32; off; off >>= 1) s += __shfl_down(s, off, 64);
    if ((tid & 63) == 0) lds4[tid >> 6] = s;
    __syncthreads();
    if (tid == 0) ws[WS_PARTIAL + blk] = lds4[0] + lds4[1] + lds4[2] + lds4[3];
}

// ---------- phase B body: per-batch MLP + coords (blocks 0..255 only) -------
__device__ __forceinline__ void phaseB(int blk, int tid,
                                       const float* __restrict__ w1,
                                       const float* __restrict__ b1,
                                       const float* __restrict__ w2,
                                       const float* __restrict__ b2,
                                       const float* __restrict__ l_t,
                                       const float* __restrict__ ws,
                                       float* __restrict__ out_weight,
                                       float2* __restrict__ coords,
                                       float* branch, float* hidden, float* wpair) {
    int b = blk >> 5;
    if (tid < C) {
        const float* pp = ws + WS_PARTIAL + (b * C + tid) * 2;
        branch[tid] = (pp[0] + pp[1]) * (1.0f / PLANE);
    }
    __syncthreads();
    if (tid < 32) {
        float h = b1[tid];
        for (int c = 0; c < C; ++c) h += branch[c] * w1[c * 32 + tid];
        hidden[tid] = h > 0.f ? h : 0.f;
    }
    __syncthreads();
    if (tid < 2) {
        float sacc = b2[tid];
        for (int m = 0; m < 32; ++m) sacc += hidden[m] * w2[m * 2 + tid];
        float wv = 1.f / (1.f + expf(-sacc));
        wpair[tid] = wv;
        if ((blk & 31) == 0) out_weight[b * 2 + tid] = wv;
    }
    __syncthreads();

    float lo = logf(wpair[0] * 0.01f);     // log(weight0 * R_MIN)
    float hi = logf(wpair[1] * 0.6f);      // log(weight1 * R_MAX)

    int p   = blk * 256 + tid;             // [0, 65536)
    int rem = p & 8191;
    int i = rem >> 7;     // row 0..63
    int j = rem & 127;    // col 0..127
    float xg = (float)(i - 32) * (1.f / 32.f);
    float yg = (float)(j - 64) * (1.f / 64.f);
    float rr = sqrtf(xg * xg + yg * yg);
    float r = 64.f * (logf(fmaxf(rr, 1e-12f)) - lo) / (hi - lo);
    float a = atan2f(yg, xg);
    if (!(a > 0.f)) a = 2.f * PI_F + a;
    float t = 0.5f * a * 64.f / PI_F;
    float gxv = t * (1.f / 32.f) - 1.f + l_t[b * 2 + 0];
    float gyv = r * (1.f / 32.f) - 1.f + l_t[b * 2 + 1];
    float ix = ((gxv + 1.f) * (float)WIN - 1.f) * 0.5f;
    float iy = ((gyv + 1.f) * (float)HIN - 1.f) * 0.5f;
    ix = fminf(fmaxf(ix, 0.f), (float)(WIN - 1));
    iy = fminf(fmaxf(iy, 0.f), (float)(HIN - 1));
    coords[p] = make_float2(ix, iy);
}

// ---------- phase C body: one 16x32-fine patch (one wave-tile quartet) ------
__device__ __forceinline__ void phaseC_unit(int unit, int tid,
                                            const float* __restrict__ x,
                                            const float2* __restrict__ coords,
                                            float* __restrict__ out) {
    int bc    = unit >> 4;
    int patch = unit & 15;
    int b     = bc >> 6;
    int pb_h  = patch >> 2;
    int pb_w  = patch & 3;

    int wave   = tid >> 6;
    int lane   = tid & 63;
    int wave_h = wave >> 1;
    int wave_w = wave & 1;
    int fi_l   = lane >> 3;        // 0..7
    int fj_l   = lane & 7;         // 0..7

    int fi  = pb_h * 16 + wave_h * 8 + fi_l;
    int fjb = pb_w * 32 + wave_w * 16;

    const float*  plane = x + (size_t)bc * PLANE;
    const float2* cb    = coords + b * NGRID + fi * 128 + fjb;

    float2 c0 = cb[fj_l];
    float2 c1 = cb[8 + fj_l];
    float a0 = bilinear(plane, c0.x, c0.y);
    float a1 = bilinear(plane, c1.x, c1.y);

    a0 += __shfl_xor(a0, 1, 64);  a1 += __shfl_xor(a1, 1, 64);
    a0 += __shfl_xor(a0, 2, 64);  a1 += __shfl_xor(a1, 2, 64);
    a0 += __shfl_xor(a0, 8, 64);  a1 += __shfl_xor(a1, 8, 64);
    a0 += __shfl_xor(a0, 16, 64); a1 += __shfl_xor(a1, 16, 64);

    if ((lane & 27) == 0) {        // lanes 0,4,32,36
        int ph = pb_h * 4 + wave_h * 2 + (fi_l >> 2);
        int pw = pb_w * 8 + wave_w * 4 + (fj_l >> 2);
        float* o = out + (size_t)bc * OUT_PER_BC + ph * 128 + pw;
        o[0] = a0 * (1.f / 16.f);
        o[2] = a1 * (1.f / 16.f);
    }
}

// ---------------- cooperative fused kernel: A | sync | B | sync | C ---------
__global__ __launch_bounds__(256, 4) void fused_all(const float* __restrict__ x,
                                                    const float* __restrict__ l_t,
                                                    const float* __restrict__ w1,
                                                    const float* __restrict__ b1,
                                                    const float* __restrict__ w2,
                                                    const float* __restrict__ b2,
                                                    float* __restrict__ ws,
                                                    float* __restrict__ out) {
    __shared__ float lds4[4];
    __shared__ float branch[C];
    __shared__ float hidden[32];
    __shared__ float wpair[2];

    cg::grid_group grid = cg::this_grid();
    int blk = blockIdx.x;          // 0..1023
    int tid = threadIdx.x;

    phaseA(blk, tid, x, l_t, ws, out, lds4);
    grid.sync();
    if (blk < 256)
        phaseB(blk, tid, w1, b1, w2, b2, l_t, ws, out + POOLED_SIZE,
               (float2*)(ws + WS_COORDS), branch, hidden, wpair);
    grid.sync();
#pragma unroll
    for (int u = 0; u < 8; ++u)    // unit = blk*8+u -> bc fixed per block
        phaseC_unit(blk * 8 + u, tid, x, (const float2*)(ws + WS_COORDS), out);
}

// ---------------- non-cooperative fallback (3 kernels) ----------------------
__global__ __launch_bounds__(256) void k1_gap_fill(const float* __restrict__ x,
                                                   const float* __restrict__ l_t,
                                                   float* __restrict__ ws,
                                                   float* __restrict__ out) {
    __shared__ float lds4[4];
    phaseA(blockIdx.x, threadIdx.x, x, l_t, ws, out, lds4);
}

__global__ __launch_bounds__(256) void k2_coords(const float* __restrict__ w1,
                                                 const float* __restrict__ b1,
                                                 const float* __restrict__ w2,
                                                 const float* __restrict__ b2,
                                                 const float* __restrict__ l_t,
                                                 const float* __restrict__ ws,
                                                 float* __restrict__ out_weight,
                                                 float2* __restrict__ coords) {
    __shared__ float branch[C];
    __shared__ float hidden[32];
    __shared__ float wpair[2];
    phaseB(blockIdx.x, threadIdx.x, w1, b1, w2, b2, l_t, ws, out_weight, coords,
           branch, hidden, wpair);
}

__global__ __launch_bounds__(256) void k3_corner(const float* __restrict__ x,
                                                 const float2* __restrict__ coords,
                                                 float* __restrict__ out) {
    phaseC_unit(blockIdx.x, threadIdx.x, x, coords, out);
}

extern "C" void kernel_launch(void* const* d_in, const int* in_sizes, int n_in,
                              void* d_out, int out_size, void* d_ws, size_t ws_size,
                              hipStream_t stream) {
    const float* x   = (const float*)d_in[0];
    const float* l_t = (const float*)d_in[1];
    const float* w1  = (const float*)d_in[2];
    const float* b1  = (const float*)d_in[3];
    const float* w2  = (const float*)d_in[4];
    const float* b2  = (const float*)d_in[5];
    float* out = (float*)d_out;
    float* ws  = (float*)d_ws;

    void* args[] = { (void*)&x, (void*)&l_t, (void*)&w1, (void*)&b1,
                     (void*)&w2, (void*)&b2, (void*)&ws, (void*)&out };
    hipError_t e = hipLaunchCooperativeKernel((const void*)fused_all,
                                              dim3(1024), dim3(256),
                                              args, 0, stream);
    if (e != hipSuccess) {
        // fallback: same phases as 3 dependent dispatches
        k1_gap_fill<<<dim3(1024), dim3(256), 0, stream>>>(x, l_t, ws, out);
        k2_coords<<<dim3(256), dim3(256), 0, stream>>>(
            w1, b1, w2, b2, l_t, ws, out + POOLED_SIZE, (float2*)(ws + WS_COORDS));
        k3_corner<<<dim3(B * C * 16), dim3(256), 0, stream>>>(
            x, (const float2*)(ws + WS_COORDS), out);
    }
}

// Round 5
// 173.826 us; speedup vs baseline: 2.3352x; 2.3352x over previous
//
#include <hip/hip_runtime.h>
#include <math.h>

#define B 8
#define C 64
#define HIN 224
#define WIN 224
#define PLANE (HIN*WIN)        // 50176
#define PLANE4 (PLANE/4)       // 12544
#define QUART (PLANE4/4)       // 3136
#define OH 64
#define OW 128
#define OUT_PER_BC (OH*OW)     // 8192
#define POOLED_SIZE (B*C*OH*OW) // 4194304

// ws layout (floats): [0, 2048) partial sums [bc][quarter]
#define WS_PARTIAL 0

#define PI_F 3.14159265358979323846f

__device__ __forceinline__ float bilinear(const float* __restrict__ p,
                                          float ix, float iy) {
    float x0f = floorf(ix), y0f = floorf(iy);
    int x0 = (int)x0f, y0 = (int)y0f;
    float wx = ix - x0f, wy = iy - y0f;
    int x1 = min(x0 + 1, WIN - 1);
    int y1 = min(y0 + 1, HIN - 1);
    const float* r0 = p + y0 * WIN;
    const float* r1 = p + y1 * WIN;
    float v00 = r0[x0], v01 = r0[x1], v10 = r1[x0], v11 = r1[x1];
    float v0 = v00 + (v01 - v00) * wx;
    float v1 = v10 + (v11 - v10) * wx;
    return v0 + (v1 - v0) * wy;
}

// ---------------- K1: gap partial sums + constant-region fill ----------------
// (round-2-verified version: 2048 blocks, quarter-plane each)
__global__ __launch_bounds__(256) void k1_gap_fill(const float* __restrict__ x,
                                                   const float* __restrict__ l_t,
                                                   float* __restrict__ ws,
                                                   float* __restrict__ out) {
    int blk = blockIdx.x;          // bc*4 + q
    int bc  = blk >> 2, q = blk & 3;
    int b   = bc >> 6;
    int tid = threadIdx.x;

    const float4* p = (const float4*)x + (size_t)bc * PLANE4 + q * QUART;
    float s = 0.f;
#pragma unroll
    for (int k = 0; k < 12; ++k) {
        float4 v = p[tid + k * 256];
        s += (v.x + v.y) + (v.z + v.w);
    }
    if (tid < QUART - 12 * 256) {  // remainder: 64 float4s
        float4 v = p[tid + 12 * 256];
        s += (v.x + v.y) + (v.z + v.w);
    }

    // Constant region: grid == (0,0)+l_t outside the 64x128 fine corner ->
    // all pooled outputs with h>=16 or w>=32 equal ONE bilinear sample.
    const float* plane = x + (size_t)bc * PLANE;
    float gx = l_t[b * 2 + 0], gy = l_t[b * 2 + 1];
    float ixc = fminf(fmaxf(((gx + 1.f) * (float)WIN - 1.f) * 0.5f, 0.f), (float)(WIN - 1));
    float iyc = fminf(fmaxf(((gy + 1.f) * (float)HIN - 1.f) * 0.5f, 0.f), (float)(HIN - 1));
    float vc = bilinear(plane, ixc, iyc);   // wave-uniform address: 1 txn
    float4 vc4 = make_float4(vc, vc, vc, vc);

    float4* o4 = (float4*)(out + (size_t)bc * OUT_PER_BC);
    if (q == 0) {
        // rows h=0..15; const part is w in [32,128) -> f4 cols 8..31
#pragma unroll
        for (int k = 0; k < 2; ++k) {
            int f4i = tid + k * 256;
            if (f4i < 384) {
                int row = f4i / 24;
                int c4  = f4i - row * 24 + 8;
                o4[row * 32 + c4] = vc4;
            }
        }
    } else {
        // h>=16, fully constant. 512 float4s.
        o4[q * 512 + tid]       = vc4;
        o4[q * 512 + 256 + tid] = vc4;
    }

    // wave (64-lane) reduce, then cross-wave via LDS
    for (int off = 32; off; off >>= 1) s += __shfl_down(s, off, 64);
    __shared__ float lds[4];
    if ((tid & 63) == 0) lds[tid >> 6] = s;
    __syncthreads();
    if (tid == 0) ws[WS_PARTIAL + blk] = lds[0] + lds[1] + lds[2] + lds[3];
}

// ---------------- K3: MLP + per-patch coords + sample 16 channels -----------
// Grid depends only on batch, so each block computes its patch's coords ONCE
// (2 register float2 per thread, 4x total redundancy vs a dedicated coords
// kernel ~= +0.3us VALU) and reuses them across a 16-channel loop. This
// removes the k2 dispatch (~4-6us of launch + boundary) without round-3's
// 64x-redundant transcendentals (+7us).
// blk = b*64 + patch*4 + cgroup; channels [cgroup*16, cgroup*16+16).
__global__ __launch_bounds__(256) void k3_combined(const float* __restrict__ x,
                                                   const float* __restrict__ w1,
                                                   const float* __restrict__ b1,
                                                   const float* __restrict__ w2,
                                                   const float* __restrict__ b2,
                                                   const float* __restrict__ l_t,
                                                   const float* __restrict__ ws,
                                                   float* __restrict__ out_weight,
                                                   float* __restrict__ out) {
    int blk   = blockIdx.x;        // 0..511
    int b     = blk >> 6;
    int g     = blk & 63;
    int patch = g >> 2;            // 0..15
    int cgrp  = g & 3;             // 0..3
    int tid   = threadIdx.x;

    __shared__ float branch[C];
    __shared__ float hidden[32];
    __shared__ float sparams[4];   // lo, hi, ltx, lty

    if (tid < C) {
        const float* pp = ws + WS_PARTIAL + (b * C + tid) * 4;
        branch[tid] = (pp[0] + pp[1] + pp[2] + pp[3]) * (1.0f / PLANE);
    }
    __syncthreads();
    if (tid < 32) {
        float h = b1[tid];
        for (int c = 0; c < C; ++c) h += branch[c] * w1[c * 32 + tid];
        hidden[tid] = h > 0.f ? h : 0.f;
    }
    __syncthreads();
    if (tid < 2) {
        float sacc = b2[tid];
        for (int m = 0; m < 32; ++m) sacc += hidden[m] * w2[m * 2 + tid];
        float wv = 1.f / (1.f + expf(-sacc));
        if (g == 0) out_weight[b * 2 + tid] = wv;
        sparams[tid]     = logf(wv * (tid == 0 ? 0.01f : 0.6f)); // lo, hi
        sparams[2 + tid] = l_t[b * 2 + tid];
    }
    __syncthreads();

    float lo = sparams[0], hi = sparams[1];
    float inv_hl = 1.f / (hi - lo);
    float ltx = sparams[2], lty = sparams[3];

    // wave-tile layout within the 16x32 fine patch (round-2 verified)
    int wave   = tid >> 6;
    int lane   = tid & 63;
    int wave_h = wave >> 1;
    int wave_w = wave & 1;
    int fi_l   = lane >> 3;        // 0..7
    int fj_l   = lane & 7;         // 0..7

    int pb_h = patch >> 2;
    int pb_w = patch & 3;
    int fi   = pb_h * 16 + wave_h * 8 + fi_l;       // fine row 0..63
    int fjb  = pb_w * 32 + wave_w * 16;
    int fj0  = fjb + fj_l;
    int fj1  = fjb + 8 + fj_l;

    // per-thread coords, computed ONCE (shared xg across both samples)
    float xg = (float)(fi - 32) * (1.f / 32.f);
    float ix0, iy0, ix1, iy1;
    {
        float yg = (float)(fj0 - 64) * (1.f / 64.f);
        float rr = sqrtf(xg * xg + yg * yg);
        float r  = 64.f * (logf(fmaxf(rr, 1e-12f)) - lo) * inv_hl;
        float a  = atan2f(yg, xg);
        if (!(a > 0.f)) a = 2.f * PI_F + a;
        float gxv = a * (1.f / PI_F) - 1.f + ltx;
        float gyv = r * (1.f / 32.f) - 1.f + lty;
        ix0 = fminf(fmaxf(((gxv + 1.f) * (float)WIN - 1.f) * 0.5f, 0.f), (float)(WIN - 1));
        iy0 = fminf(fmaxf(((gyv + 1.f) * (float)HIN - 1.f) * 0.5f, 0.f), (float)(HIN - 1));
    }
    {
        float yg = (float)(fj1 - 64) * (1.f / 64.f);
        float rr = sqrtf(xg * xg + yg * yg);
        float r  = 64.f * (logf(fmaxf(rr, 1e-12f)) - lo) * inv_hl;
        float a  = atan2f(yg, xg);
        if (!(a > 0.f)) a = 2.f * PI_F + a;
        float gxv = a * (1.f / PI_F) - 1.f + ltx;
        float gyv = r * (1.f / 32.f) - 1.f + lty;
        ix1 = fminf(fmaxf(((gxv + 1.f) * (float)WIN - 1.f) * 0.5f, 0.f), (float)(WIN - 1));
        iy1 = fminf(fmaxf(((gyv + 1.f) * (float)HIN - 1.f) * 0.5f, 0.f), (float)(HIN - 1));
    }

    bool writer = ((lane & 27) == 0);               // lanes 0,4,32,36
    int ph = pb_h * 4 + wave_h * 2 + (fi_l >> 2);
    int pw = pb_w * 8 + wave_w * 4 + (fj_l >> 2);

    int bc0 = b * C + cgrp * 16;
    const float* plane = x + (size_t)bc0 * PLANE;
    float* obase = out + (size_t)bc0 * OUT_PER_BC + ph * 128 + pw;

    // 16 channels, unrolled x2 -> 16 independent gathers in flight per thread
#pragma unroll
    for (int cc = 0; cc < 16; cc += 2) {
        float a0 = bilinear(plane, ix0, iy0);
        float a1 = bilinear(plane, ix1, iy1);
        float b0 = bilinear(plane + PLANE, ix0, iy0);
        float b1v = bilinear(plane + PLANE, ix1, iy1);

        a0 += __shfl_xor(a0, 1, 64);  a1 += __shfl_xor(a1, 1, 64);
        b0 += __shfl_xor(b0, 1, 64);  b1v += __shfl_xor(b1v, 1, 64);
        a0 += __shfl_xor(a0, 2, 64);  a1 += __shfl_xor(a1, 2, 64);
        b0 += __shfl_xor(b0, 2, 64);  b1v += __shfl_xor(b1v, 2, 64);
        a0 += __shfl_xor(a0, 8, 64);  a1 += __shfl_xor(a1, 8, 64);
        b0 += __shfl_xor(b0, 8, 64);  b1v += __shfl_xor(b1v, 8, 64);
        a0 += __shfl_xor(a0, 16, 64); a1 += __shfl_xor(a1, 16, 64);
        b0 += __shfl_xor(b0, 16, 64); b1v += __shfl_xor(b1v, 16, 64);

        if (writer) {
            obase[0] = a0 * (1.f / 16.f);
            obase[2] = a1 * (1.f / 16.f);
            obase[OUT_PER_BC]     = b0  * (1.f / 16.f);
            obase[OUT_PER_BC + 2] = b1v * (1.f / 16.f);
        }
        plane += 2 * PLANE;
        obase += 2 * OUT_PER_BC;
    }
}

extern "C" void kernel_launch(void* const* d_in, const int* in_sizes, int n_in,
                              void* d_out, int out_size, void* d_ws, size_t ws_size,
                              hipStream_t stream) {
    const float* x   = (const float*)d_in[0];
    const float* l_t = (const float*)d_in[1];
    const float* w1  = (const float*)d_in[2];
    const float* b1  = (const float*)d_in[3];
    const float* w2  = (const float*)d_in[4];
    const float* b2  = (const float*)d_in[5];
    float* out = (float*)d_out;
    float* ws  = (float*)d_ws;

    k1_gap_fill<<<dim3(B * C * 4), dim3(256), 0, stream>>>(x, l_t, ws, out);
    k3_combined<<<dim3(B * C), dim3(256), 0, stream>>>(
        x, w1, b1, w2, b2, l_t, ws, out + POOLED_SIZE, out);
}